// Round 8
// baseline (198.030 us; speedup 1.0000x reference)
//
#include <hip/hip_runtime.h>
#include <math.h>

// SoftMoE fp32: B=4,S=4096,D=768,E=16,SLOTS=1,H=3072
constexpr int B = 4, S = 4096, D = 768, E = 16, N = 16, H = 3072;
constexpr int SCH = 16;            // s-chunk length for xs partials
constexpr int NSCH = S / SCH;      // 256 chunks
constexpr int DL1 = 24;            // d-rows per ffn1 block
constexpr int NDC = D / DL1;       // 32
constexpr int NHH = 3;             // h-thirds (1024 cols) per ffn1 block
constexpr int HL2 = 24;            // h-rows per ffn2 block
constexpr int NHC2 = H / HL2;      // 128
constexpr int LBLK = 16;           // rows per logits block
constexpr int LPB = S / LBLK;      // logits blocks per b = 256

// workspace layout (float offsets)
constexpr size_t OFF_LOG  = 0;                                   // B*S*N
constexpr size_t OFF_DW   = OFF_LOG + (size_t)B * S * N;         // B*S*N
constexpr size_t OFF_PCM  = OFF_DW + (size_t)B * S * N;          // B*LPB*N
constexpr size_t OFF_PCS  = OFF_PCM + (size_t)B * LPB * N;       // B*LPB*N
constexpr size_t OFF_CMAX = OFF_PCS + (size_t)B * LPB * N;       // B*N
constexpr size_t OFF_CSUM = OFF_CMAX + (size_t)B * N;            // B*N
constexpr size_t OFF_XSP  = OFF_CSUM + (size_t)B * N;            // B*NSCH*N*D
constexpr size_t OFF_XS   = OFF_XSP + (size_t)B * NSCH * N * D;  // B*N*D
constexpr size_t OFF_HP   = OFF_XS + (size_t)B * N * D;          // NDC*B*E*H
constexpr size_t OFF_YSP  = OFF_HP + (size_t)NDC * B * E * H;    // NHC2*B*E*D
constexpr size_t OFF_YS   = OFF_YSP + (size_t)NHC2 * B * E * D;  // B*E*D

__device__ __forceinline__ void fma4(float4& a, float s, const float4& w) {
    a.x = fmaf(s, w.x, a.x);
    a.y = fmaf(s, w.y, a.y);
    a.z = fmaf(s, w.z, a.z);
    a.w = fmaf(s, w.w, a.w);
}

// ---------------- K1: logits + dispatch softmax + combine-stats partials ----
// grid: B*LPB = 1024 blocks, 256 threads. 16-lane group handles ONE row.
__global__ __launch_bounds__(256) void k_logits(const float* __restrict__ x,
                                                const float* __restrict__ phi,
                                                float* __restrict__ logits,
                                                float* __restrict__ dw,
                                                float* __restrict__ pcm,
                                                float* __restrict__ pcs) {
    __shared__ float ph[16][D];
    __shared__ float rm[16][16];
    const int t = threadIdx.x;
    const int blk = blockIdx.x;
    const int b = blk / LPB;
    const int s0 = (blk % LPB) * LBLK;

#pragma unroll
    for (int i = 0; i < 12; ++i) {
        const int idx = i * 1024 + t * 4;
        const float4 v = *reinterpret_cast<const float4*>(phi + idx);
        const int d0 = idx >> 4;
        const int n0 = idx & 15;
        ph[n0 + 0][d0] = v.x;
        ph[n0 + 1][d0] = v.y;
        ph[n0 + 2][d0] = v.z;
        ph[n0 + 3][d0] = v.w;
    }
    __syncthreads();

    const int gid = t >> 4;
    const int ln = t & 15;
    const int s = s0 + gid;
    const float* xr0 = x + ((size_t)b * S + s) * D;

    float4 a0[12];
#pragma unroll
    for (int j = 0; j < 12; ++j)
        a0[j] = *reinterpret_cast<const float4*>(xr0 + j * 64 + ln * 4);

    float p0[16];
#pragma unroll
    for (int n = 0; n < 16; ++n) {
        float q0 = 0.f;
#pragma unroll
        for (int j = 0; j < 12; ++j) {
            const float4 pv = *reinterpret_cast<const float4*>(&ph[n][j * 64 + ln * 4]);
            q0 = fmaf(a0[j].x, pv.x, q0);
            q0 = fmaf(a0[j].y, pv.y, q0);
            q0 = fmaf(a0[j].z, pv.z, q0);
            q0 = fmaf(a0[j].w, pv.w, q0);
        }
        p0[n] = q0;
    }
#pragma unroll
    for (int m = 1; m < 16; m <<= 1) {
#pragma unroll
        for (int n = 0; n < 16; ++n) p0[n] += __shfl_xor(p0[n], m, 64);
    }
    float m0 = -1e30f;
#pragma unroll
    for (int n = 0; n < 16; ++n) m0 = fmaxf(m0, p0[n]);
    float su0 = 0.f;
#pragma unroll
    for (int n = 0; n < 16; ++n) su0 += __expf(p0[n] - m0);
    const size_t o0 = ((size_t)b * S + s) * N + ln;
    logits[o0] = p0[ln];
    dw[o0] = __expf(p0[ln] - m0) / su0;

    // combine-stats partial: per-row max is the value itself (1 row/group)
    rm[gid][ln] = p0[ln];
    __syncthreads();
    if (t < 16) {  // t = n; LSE-merge the 16 rows of this block
        float M = -1e30f;
#pragma unroll
        for (int g = 0; g < 16; ++g) M = fmaxf(M, rm[g][t]);
        float SS = 0.f;
#pragma unroll
        for (int g = 0; g < 16; ++g) SS += __expf(rm[g][t] - M);
        pcm[blk * 16 + t] = M;
        pcs[blk * 16 + t] = SS;
    }
}

// ---------------- K2: xs partials ----------------
// grid: B*NSCH = 1024 blocks, 192 threads (thread owns 4 d via float4)
__global__ __launch_bounds__(192) void k_xsp(const float* __restrict__ x,
                                             const float* __restrict__ dw,
                                             float* __restrict__ xsp) {
    const int blk = blockIdx.x;
    const int b = blk / NSCH;
    const int c = blk % NSCH;
    const int t = threadIdx.x;
    const int d = t * 4;
    float4 a[16];
#pragma unroll
    for (int n = 0; n < 16; ++n) a[n] = float4{0.f, 0.f, 0.f, 0.f};
    const float* xb = x + ((size_t)b * S + (size_t)c * SCH) * D + d;
    const float* dwb = dw + ((size_t)b * S + (size_t)c * SCH) * N;
#pragma unroll 2
    for (int s = 0; s < SCH; ++s) {
        const float4 xv = *reinterpret_cast<const float4*>(xb + (size_t)s * D);
#pragma unroll
        for (int n = 0; n < 16; ++n) {
            const float w = dwb[s * N + n];
            a[n].x = fmaf(w, xv.x, a[n].x);
            a[n].y = fmaf(w, xv.y, a[n].y);
            a[n].z = fmaf(w, xv.z, a[n].z);
            a[n].w = fmaf(w, xv.w, a[n].w);
        }
    }
    float* o = xsp + (size_t)blk * N * D + d;
#pragma unroll
    for (int n = 0; n < 16; ++n)
        *reinterpret_cast<float4*>(o + (size_t)n * D) = a[n];
}

// ---------------- K3: reduce xs partials + merge combine stats ----------------
// grid: 193 blocks. 0..191: xsred (256 thr). 192: cmerge (t<64).
__global__ __launch_bounds__(256) void k_xsred_cmerge(const float* __restrict__ xsp,
                                                      float* __restrict__ xs,
                                                      const float* __restrict__ pcm,
                                                      const float* __restrict__ pcs,
                                                      float* __restrict__ cmax,
                                                      float* __restrict__ csum) {
    const int t = threadIdx.x;
    if (blockIdx.x < 192) {
        const int i = blockIdx.x * 256 + t;      // over B*N*D
        const int b = i / (N * D);
        const int rem = i % (N * D);
        const float* p = xsp + (size_t)b * NSCH * N * D + rem;
        float sum = 0.f;
#pragma unroll 8
        for (int c = 0; c < NSCH; ++c) sum += p[(size_t)c * N * D];
        xs[i] = sum;
    } else if (t < 64) {
        const int b = t >> 4, n = t & 15;
        float M = -1e30f;
#pragma unroll 8
        for (int c = 0; c < LPB; ++c) M = fmaxf(M, pcm[((size_t)b * LPB + c) * 16 + n]);
        float SS = 0.f;
#pragma unroll 8
        for (int c = 0; c < LPB; ++c)
            SS += pcs[((size_t)b * LPB + c) * 16 + n] * __expf(pcm[((size_t)b * LPB + c) * 16 + n] - M);
        cmax[b * 16 + n] = M;
        csum[b * 16 + n] = SS;
    }
}

// ---------------- K4: FFN1 (h-partial = xs @ W1) ----------------
// grid: E*NDC*NHH = 16*32*3 = 1536 blocks, 256 threads -> 24 waves/CU.
// Block = (e, 24-d-row chunk, 1024-col third). 1 float4 load + 16 FMA per iter.
__global__ __launch_bounds__(256) void k_ffn1(const float* __restrict__ xs,
                                              const float* __restrict__ W1,
                                              float* __restrict__ hp) {
    __shared__ __align__(16) float xs_lds[DL1][4];
    const int t = threadIdx.x;
    const int e = blockIdx.x / (NDC * NHH);
    const int rem = blockIdx.x % (NDC * NHH);
    const int dc = rem / NHH;
    const int hh = rem % NHH;
    const int d0 = dc * DL1;
    const int col = hh * 1024 + t * 4;

    if (t < DL1 * 4) {
        const int dd = t >> 2, b = t & 3;
        xs_lds[dd][b] = xs[((size_t)b * N + e) * D + d0 + dd];
    }
    __syncthreads();

    float4 acc[4];
#pragma unroll
    for (int b = 0; b < 4; ++b) acc[b] = float4{0.f, 0.f, 0.f, 0.f};

    const float* wp = W1 + ((size_t)e * D + d0) * H + col;
#pragma unroll 8
    for (int dd = 0; dd < DL1; ++dd) {
        const float4 w = *reinterpret_cast<const float4*>(wp + (size_t)dd * H);
        const float4 xv = *reinterpret_cast<const float4*>(&xs_lds[dd][0]);  // wave-uniform
        fma4(acc[0], xv.x, w);
        fma4(acc[1], xv.y, w);
        fma4(acc[2], xv.z, w);
        fma4(acc[3], xv.w, w);
    }
    // hp layout: [dc][b][e][h]
#pragma unroll
    for (int b = 0; b < 4; ++b)
        *reinterpret_cast<float4*>(hp + (((size_t)dc * 4 + b) * E + e) * H + col) = acc[b];
}

// ---------------- K5: FFN2 + fused hp-reduce + bias + exact GELU ----------------
// grid: E*NHC2 = 16*128 = 2048 blocks, 192 threads -> 24 waves/CU.
// Block = (e, 24-h-row chunk). Phase 0: reduce hp + GELU -> LDS.
// Phase 1: stream contiguous 72 KB W2 span, 1 load + 16 FMA per iter.
__global__ __launch_bounds__(192) void k_ffn2(const float* __restrict__ hp,
                                              const float* __restrict__ b1,
                                              const float* __restrict__ W2,
                                              float* __restrict__ ysp) {
    __shared__ __align__(16) float g_lds[HL2][4];
    __shared__ float r_lds[2][96];
    const int t = threadIdx.x;
    const int e = blockIdx.x / NHC2;
    const int hc = blockIdx.x % NHC2;
    const int h0 = hc * HL2;

    {
        const int half = t / 96;    // dc range: half*16 .. half*16+15
        const int pair = t % 96;
        const int b = pair / HL2;   // 0..3
        const int hh = pair % HL2;  // 0..23
        float v = 0.f;
#pragma unroll
        for (int i = 0; i < 16; ++i) {
            const int dc = half * 16 + i;
            v += hp[(((size_t)dc * 4 + b) * E + e) * H + h0 + hh];
        }
        r_lds[half][pair] = v;
    }
    __syncthreads();
    if (t < 96) {
        const int b = t / HL2, hh = t % HL2;
        float v = r_lds[0][t] + r_lds[1][t] + b1[(size_t)e * H + h0 + hh];
        v = 0.5f * v * (1.0f + erff(v * 0.70710678118654752f));
        g_lds[hh][b] = v;
    }
    __syncthreads();

    float4 acc[4];
#pragma unroll
    for (int b = 0; b < 4; ++b) acc[b] = float4{0.f, 0.f, 0.f, 0.f};

    const float* wp = W2 + ((size_t)e * H + h0) * D + t * 4;
#pragma unroll 8
    for (int kk = 0; kk < HL2; ++kk) {
        const float4 w = *reinterpret_cast<const float4*>(wp + (size_t)kk * D);
        const float4 hv = *reinterpret_cast<const float4*>(&g_lds[kk][0]);  // wave-uniform
        fma4(acc[0], hv.x, w);
        fma4(acc[1], hv.y, w);
        fma4(acc[2], hv.z, w);
        fma4(acc[3], hv.w, w);
    }
    // ysp layout: [hc][b][e][d]
#pragma unroll
    for (int b = 0; b < 4; ++b)
        *reinterpret_cast<float4*>(ysp + (((size_t)hc * 4 + b) * E + e) * D + t * 4) = acc[b];
}

// ---------------- K6: reduce ys partials + b2 (float4) ----------------
// grid: 192 blocks x 64 thr (spread across CUs; 12288 float4s total)
__global__ __launch_bounds__(64) void k_ysred(const float* __restrict__ ysp,
                                              const float* __restrict__ b2,
                                              float* __restrict__ ys) {
    const int i4 = blockIdx.x * 64 + threadIdx.x;   // over B*E*D/4
    const int rem4 = i4 % (E * D / 4);
    float4 v = *reinterpret_cast<const float4*>(b2 + (size_t)rem4 * 4);
#pragma unroll 8
    for (int hc = 0; hc < NHC2; ++hc) {
        const float4 u = *reinterpret_cast<const float4*>(ysp + (size_t)hc * B * E * D + (size_t)i4 * 4);
        v.x += u.x; v.y += u.y; v.z += u.z; v.w += u.w;
    }
    *reinterpret_cast<float4*>(ys + (size_t)i4 * 4) = v;
}

// ---------------- K7: combine ----------------
// grid: B*S/8 = 2048 blocks, 192 threads; block handles 8 s-rows; ys hoisted to regs
__global__ __launch_bounds__(192) void k_combine(const float* __restrict__ logits,
                                                 const float* __restrict__ cmax,
                                                 const float* __restrict__ csum,
                                                 const float* __restrict__ ys,
                                                 float* __restrict__ y) {
    const int blk = blockIdx.x;
    const int b = blk / (S / 8);
    const int s0 = (blk % (S / 8)) * 8;
    const int t = threadIdx.x;
    const int d4 = t * 4;

    float4 ysr[16];
    float cm[16], ci[16];
#pragma unroll
    for (int n = 0; n < 16; ++n) {
        ysr[n] = *reinterpret_cast<const float4*>(ys + ((size_t)b * N + n) * D + d4);
        cm[n] = cmax[b * N + n];
        ci[n] = 1.0f / csum[b * N + n];
    }
#pragma unroll
    for (int r = 0; r < 8; ++r) {
        const int s = s0 + r;
        const float* lrow = logits + ((size_t)b * S + s) * N;
        float4 acc{0, 0, 0, 0};
#pragma unroll
        for (int n = 0; n < 16; ++n) {
            const float cw = __expf(lrow[n] - cm[n]) * ci[n];
            acc.x = fmaf(cw, ysr[n].x, acc.x);
            acc.y = fmaf(cw, ysr[n].y, acc.y);
            acc.z = fmaf(cw, ysr[n].z, acc.z);
            acc.w = fmaf(cw, ysr[n].w, acc.w);
        }
        *reinterpret_cast<float4*>(y + ((size_t)b * S + s) * D + d4) = acc;
    }
}

extern "C" void kernel_launch(void* const* d_in, const int* in_sizes, int n_in,
                              void* d_out, int out_size, void* d_ws, size_t ws_size,
                              hipStream_t stream) {
    const float* x   = (const float*)d_in[0];
    const float* phi = (const float*)d_in[1];
    const float* W1  = (const float*)d_in[2];
    const float* b1  = (const float*)d_in[3];
    const float* W2  = (const float*)d_in[4];
    const float* b2  = (const float*)d_in[5];
    float* y = (float*)d_out;
    float* ws = (float*)d_ws;

    float* logits = ws + OFF_LOG;
    float* dw     = ws + OFF_DW;
    float* pcm    = ws + OFF_PCM;
    float* pcs    = ws + OFF_PCS;
    float* cmax   = ws + OFF_CMAX;
    float* csum   = ws + OFF_CSUM;
    float* xsp    = ws + OFF_XSP;
    float* xs     = ws + OFF_XS;
    float* hp     = ws + OFF_HP;
    float* ysp    = ws + OFF_YSP;
    float* ys     = ws + OFF_YS;

    k_logits<<<B * LPB, 256, 0, stream>>>(x, phi, logits, dw, pcm, pcs);
    k_xsp<<<B * NSCH, 192, 0, stream>>>(x, dw, xsp);
    k_xsred_cmerge<<<193, 256, 0, stream>>>(xsp, xs, pcm, pcs, cmax, csum);
    k_ffn1<<<E * NDC * NHH, 256, 0, stream>>>(xs, W1, hp);
    k_ffn2<<<E * NHC2, 192, 0, stream>>>(hp, b1, W2, ysp);
    k_ysred<<<192, 64, 0, stream>>>(ysp, b2, ys);
    k_combine<<<B * (S / 8), 192, 0, stream>>>(logits, cmax, csum, ys, y);
}

// Round 9
// 153.810 us; speedup vs baseline: 1.2875x; 1.2875x over previous
//
#include <hip/hip_runtime.h>
#include <math.h>

// SoftMoE fp32: B=4,S=4096,D=768,E=16,SLOTS=1,H=3072
constexpr int B = 4, S = 4096, D = 768, E = 16, N = 16, H = 3072;
constexpr int SCH = 32;            // s-chunk length for xs partials
constexpr int NSCH = S / SCH;      // 128 chunks
constexpr int HL = 96;             // h-chunk in fused FFN
constexpr int NHC = H / HL;        // 32
constexpr int LBLK = 32;           // rows per logits block
constexpr int LPB = S / LBLK;      // logits blocks per b = 128

// workspace layout (float offsets)
constexpr size_t OFF_LOG  = 0;                                   // B*S*N
constexpr size_t OFF_DW   = OFF_LOG + (size_t)B * S * N;         // B*S*N
constexpr size_t OFF_PCM  = OFF_DW + (size_t)B * S * N;          // B*LPB*N
constexpr size_t OFF_PCS  = OFF_PCM + (size_t)B * LPB * N;       // B*LPB*N
constexpr size_t OFF_CMAX = OFF_PCS + (size_t)B * LPB * N;       // B*N
constexpr size_t OFF_CSUM = OFF_CMAX + (size_t)B * N;            // B*N
constexpr size_t OFF_XSP  = OFF_CSUM + (size_t)B * N;            // B*NSCH*N*D
constexpr size_t OFF_XS   = OFF_XSP + (size_t)B * NSCH * N * D;  // B*N*D
constexpr size_t OFF_YSP  = OFF_XS + (size_t)B * N * D;          // NHC*B*E*D
constexpr size_t OFF_YS   = OFF_YSP + (size_t)NHC * B * E * D;   // B*E*D

__device__ __forceinline__ void fma4(float4& a, float s, const float4& w) {
    a.x = fmaf(s, w.x, a.x);
    a.y = fmaf(s, w.y, a.y);
    a.z = fmaf(s, w.z, a.z);
    a.w = fmaf(s, w.w, a.w);
}

// ---------------- K1: logits + dispatch softmax + combine-stats partials ----
// grid: B*LPB = 512 blocks, 256 threads. 16-lane group handles 2 rows.
__global__ __launch_bounds__(256) void k_logits(const float* __restrict__ x,
                                                const float* __restrict__ phi,
                                                float* __restrict__ logits,
                                                float* __restrict__ dw,
                                                float* __restrict__ pcm,
                                                float* __restrict__ pcs) {
    __shared__ float ph[16][D];
    __shared__ float rm[16][16], rs[16][16];
    const int t = threadIdx.x;
    const int blk = blockIdx.x;
    const int b = blk / LPB;
    const int s0 = (blk % LPB) * LBLK;

#pragma unroll
    for (int i = 0; i < 12; ++i) {
        const int idx = i * 1024 + t * 4;
        const float4 v = *reinterpret_cast<const float4*>(phi + idx);
        const int d0 = idx >> 4;
        const int n0 = idx & 15;
        ph[n0 + 0][d0] = v.x;
        ph[n0 + 1][d0] = v.y;
        ph[n0 + 2][d0] = v.z;
        ph[n0 + 3][d0] = v.w;
    }
    __syncthreads();

    const int gid = t >> 4;
    const int ln = t & 15;
    const int s = s0 + gid * 2;
    const float* xr0 = x + ((size_t)b * S + s) * D;
    const float* xr1 = xr0 + D;

    float4 a0[12], a1[12];
#pragma unroll
    for (int j = 0; j < 12; ++j) {
        a0[j] = *reinterpret_cast<const float4*>(xr0 + j * 64 + ln * 4);
        a1[j] = *reinterpret_cast<const float4*>(xr1 + j * 64 + ln * 4);
    }
    float p0[16], p1[16];
#pragma unroll
    for (int n = 0; n < 16; ++n) {
        float q0 = 0.f, q1 = 0.f;
#pragma unroll
        for (int j = 0; j < 12; ++j) {
            const float4 pv = *reinterpret_cast<const float4*>(&ph[n][j * 64 + ln * 4]);
            q0 = fmaf(a0[j].x, pv.x, q0); q1 = fmaf(a1[j].x, pv.x, q1);
            q0 = fmaf(a0[j].y, pv.y, q0); q1 = fmaf(a1[j].y, pv.y, q1);
            q0 = fmaf(a0[j].z, pv.z, q0); q1 = fmaf(a1[j].z, pv.z, q1);
            q0 = fmaf(a0[j].w, pv.w, q0); q1 = fmaf(a1[j].w, pv.w, q1);
        }
        p0[n] = q0; p1[n] = q1;
    }
#pragma unroll
    for (int m = 1; m < 16; m <<= 1) {
#pragma unroll
        for (int n = 0; n < 16; ++n) {
            p0[n] += __shfl_xor(p0[n], m, 64);
            p1[n] += __shfl_xor(p1[n], m, 64);
        }
    }
    float m0 = -1e30f, m1 = -1e30f;
#pragma unroll
    for (int n = 0; n < 16; ++n) { m0 = fmaxf(m0, p0[n]); m1 = fmaxf(m1, p1[n]); }
    float su0 = 0.f, su1 = 0.f;
#pragma unroll
    for (int n = 0; n < 16; ++n) { su0 += __expf(p0[n] - m0); su1 += __expf(p1[n] - m1); }
    const size_t o0 = ((size_t)b * S + s) * N + ln;
    logits[o0] = p0[ln];
    logits[o0 + N] = p1[ln];
    dw[o0] = __expf(p0[ln] - m0) / su0;
    dw[o0 + N] = __expf(p1[ln] - m1) / su1;

    const float mm = fmaxf(p0[ln], p1[ln]);
    const float ss = __expf(p0[ln] - mm) + __expf(p1[ln] - mm);
    rm[gid][ln] = mm;
    rs[gid][ln] = ss;
    __syncthreads();
    if (t < 16) {
        float M = -1e30f;
#pragma unroll
        for (int g = 0; g < 16; ++g) M = fmaxf(M, rm[g][t]);
        float SS = 0.f;
#pragma unroll
        for (int g = 0; g < 16; ++g) SS += rs[g][t] * __expf(rm[g][t] - M);
        pcm[blk * 16 + t] = M;
        pcs[blk * 16 + t] = SS;
    }
}

// ---------------- K2: xs partials ----------------
// grid: B*NSCH = 512 blocks, 192 threads (thread owns 4 d via float4)
__global__ __launch_bounds__(192) void k_xsp(const float* __restrict__ x,
                                             const float* __restrict__ dw,
                                             float* __restrict__ xsp) {
    const int blk = blockIdx.x;
    const int b = blk / NSCH;
    const int c = blk % NSCH;
    const int t = threadIdx.x;
    const int d = t * 4;
    float4 a[16];
#pragma unroll
    for (int n = 0; n < 16; ++n) a[n] = float4{0.f, 0.f, 0.f, 0.f};
    const float* xb = x + ((size_t)b * S + (size_t)c * SCH) * D + d;
    const float* dwb = dw + ((size_t)b * S + (size_t)c * SCH) * N;
#pragma unroll 2
    for (int s = 0; s < SCH; ++s) {
        const float4 xv = *reinterpret_cast<const float4*>(xb + (size_t)s * D);
#pragma unroll
        for (int n = 0; n < 16; ++n) {
            const float w = dwb[s * N + n];
            a[n].x = fmaf(w, xv.x, a[n].x);
            a[n].y = fmaf(w, xv.y, a[n].y);
            a[n].z = fmaf(w, xv.z, a[n].z);
            a[n].w = fmaf(w, xv.w, a[n].w);
        }
    }
    float* o = xsp + (size_t)blk * N * D + d;
#pragma unroll
    for (int n = 0; n < 16; ++n)
        *reinterpret_cast<float4*>(o + (size_t)n * D) = a[n];
}

// ---------------- K3: reduce xs partials + merge combine stats ----------------
// grid: 193 blocks. 0..191: xsred (256 thr). 192: cmerge (t<64).
__global__ __launch_bounds__(256) void k_xsred_cmerge(const float* __restrict__ xsp,
                                                      float* __restrict__ xs,
                                                      const float* __restrict__ pcm,
                                                      const float* __restrict__ pcs,
                                                      float* __restrict__ cmax,
                                                      float* __restrict__ csum) {
    const int t = threadIdx.x;
    if (blockIdx.x < 192) {
        const int i = blockIdx.x * 256 + t;      // over B*N*D
        const int b = i / (N * D);
        const int rem = i % (N * D);
        const float* p = xsp + (size_t)b * NSCH * N * D + rem;
        float sum = 0.f;
#pragma unroll 4
        for (int c = 0; c < NSCH; ++c) sum += p[(size_t)c * N * D];
        xs[i] = sum;
    } else if (t < 64) {
        const int b = t >> 4, n = t & 15;
        float M = -1e30f;
#pragma unroll 8
        for (int c = 0; c < LPB; ++c) M = fmaxf(M, pcm[((size_t)b * LPB + c) * 16 + n]);
        float SS = 0.f;
#pragma unroll 8
        for (int c = 0; c < LPB; ++c)
            SS += pcs[((size_t)b * LPB + c) * 16 + n] * __expf(pcm[((size_t)b * LPB + c) * 16 + n] - M);
        cmax[b * 16 + n] = M;
        csum[b * 16 + n] = SS;
    }
}

// ---------------- K4: fused FFN (xs @ W1 -> GELU -> @ W2 partial) ----------------
// grid: E*NHC = 512 blocks, 384 threads. Block = (e, h-chunk of HL=96).
// vs r5: all-thread reduce, no yq_lds (xs_lds reused as partner buffer),
// W2 preload issued before the reduce (T14 async-split). LDS 61.5 -> 37.5 KB.
__global__ __launch_bounds__(384) void k_ffn(const float* __restrict__ xs,
                                             const float* __restrict__ W1,
                                             const float* __restrict__ b1,
                                             const float* __restrict__ W2,
                                             float* __restrict__ ysp) {
    __shared__ __align__(16) float xs_lds[D][4];       // 12 KB (reused in phase 2)
    __shared__ __align__(16) float red_lds[16][HL][4]; // 24 KB
    __shared__ __align__(16) float h_lds[HL][4];       // 1.5 KB

    const int t = threadIdx.x;
    const int e = blockIdx.x / NHC;
    const int hc = blockIdx.x % NHC;
    const int h0 = hc * HL;

    // phase 0: stage xs[:, e, :] transposed -> xs_lds[d][b]
    for (int idx = t; idx < D; idx += 384) {
#pragma unroll
        for (int b = 0; b < 4; ++b)
            xs_lds[idx][b] = xs[((size_t)b * N + e) * D + idx];
    }
    __syncthreads();

    // phase 1: h[b][col] = sum_d xs[b][d] * W1[e][d][h0+col]
    {
        const int c4 = (t % 24) * 4;        // 4 cols
        const int q = t / 24;               // 0..15, d-range [q*48, q*48+48)
        float4 h0a{0,0,0,0}, h1a{0,0,0,0}, h2a{0,0,0,0}, h3a{0,0,0,0};
        const float* w1p = W1 + ((size_t)e * D + (size_t)q * 48) * H + h0 + c4;
#pragma unroll 8
        for (int dd = 0; dd < 48; ++dd) {
            const float4 w = *reinterpret_cast<const float4*>(w1p + (size_t)dd * H);
            const float* xv = &xs_lds[q * 48 + dd][0];
            const float x0 = xv[0], x1 = xv[1], x2 = xv[2], x3 = xv[3];
            h0a.x = fmaf(x0, w.x, h0a.x); h0a.y = fmaf(x0, w.y, h0a.y);
            h0a.z = fmaf(x0, w.z, h0a.z); h0a.w = fmaf(x0, w.w, h0a.w);
            h1a.x = fmaf(x1, w.x, h1a.x); h1a.y = fmaf(x1, w.y, h1a.y);
            h1a.z = fmaf(x1, w.z, h1a.z); h1a.w = fmaf(x1, w.w, h1a.w);
            h2a.x = fmaf(x2, w.x, h2a.x); h2a.y = fmaf(x2, w.y, h2a.y);
            h2a.z = fmaf(x2, w.z, h2a.z); h2a.w = fmaf(x2, w.w, h2a.w);
            h3a.x = fmaf(x3, w.x, h3a.x); h3a.y = fmaf(x3, w.y, h3a.y);
            h3a.z = fmaf(x3, w.z, h3a.z); h3a.w = fmaf(x3, w.w, h3a.w);
        }
        *reinterpret_cast<float4*>(&red_lds[q][c4 + 0][0]) = float4{h0a.x, h1a.x, h2a.x, h3a.x};
        *reinterpret_cast<float4*>(&red_lds[q][c4 + 1][0]) = float4{h0a.y, h1a.y, h2a.y, h3a.y};
        *reinterpret_cast<float4*>(&red_lds[q][c4 + 2][0]) = float4{h0a.z, h1a.z, h2a.z, h3a.z};
        *reinterpret_cast<float4*>(&red_lds[q][c4 + 3][0]) = float4{h0a.w, h1a.w, h2a.w, h3a.w};
    }
    __syncthreads();

    // T14: issue first 8 W2 loads per thread BEFORE the reduce (keeps memory busy)
    const int dgrp = t % 192;
    const int kq = t / 192;             // 0/1, k-range [kq*48, kq*48+48)
    const float* w2p = W2 + ((size_t)e * H + h0 + (size_t)kq * 48) * D + dgrp * 4;
    float4 wpre[8];
#pragma unroll
    for (int i = 0; i < 8; ++i)
        wpre[i] = *reinterpret_cast<const float4*>(w2p + (size_t)i * D);

    // reduce with ALL 384 threads: t -> (col = t/4, b = t&3), then bias + GELU
    {
        const int col = t >> 2, b = t & 3;
        float s = 0.f;
#pragma unroll
        for (int q = 0; q < 16; ++q) s += red_lds[q][col][b];
        s += b1[(size_t)e * H + h0 + col];
        s = 0.5f * s * (1.0f + erff(s * 0.70710678118654752f));
        h_lds[col][b] = s;
    }
    __syncthreads();

    // phase 2: ys-partial[b][d] = sum_k gelu_h[b][k] * W2[e][h0+k][d]
    float4 acc[4];
#pragma unroll
    for (int b = 0; b < 4; ++b) acc[b] = float4{0.f, 0.f, 0.f, 0.f};

#pragma unroll
    for (int kk = 0; kk < 8; ++kk) {
        const float4 hv = *reinterpret_cast<const float4*>(&h_lds[kq * 48 + kk][0]);
        fma4(acc[0], hv.x, wpre[kk]);
        fma4(acc[1], hv.y, wpre[kk]);
        fma4(acc[2], hv.z, wpre[kk]);
        fma4(acc[3], hv.w, wpre[kk]);
    }
#pragma unroll 8
    for (int kk = 8; kk < 48; ++kk) {
        const float4 w = *reinterpret_cast<const float4*>(w2p + (size_t)kk * D);
        const float4 hv = *reinterpret_cast<const float4*>(&h_lds[kq * 48 + kk][0]);
        fma4(acc[0], hv.x, w);
        fma4(acc[1], hv.y, w);
        fma4(acc[2], hv.z, w);
        fma4(acc[3], hv.w, w);
    }

    // combine the two k-halves: kq=1 writes to reused xs_lds, kq=0 adds + stores
    float4* pbuf = reinterpret_cast<float4*>(&xs_lds[0][0]);   // 192*4 float4 = 12 KB
    __syncthreads();   // all xs_lds readers done long ago; ensure phase-2 entry aligned
    if (kq == 1) {
#pragma unroll
        for (int b = 0; b < 4; ++b) pbuf[dgrp * 4 + b] = acc[b];
    }
    __syncthreads();
    if (kq == 0) {
#pragma unroll
        for (int b = 0; b < 4; ++b) {
            const float4 u = pbuf[dgrp * 4 + b];
            float4 r{acc[b].x + u.x, acc[b].y + u.y, acc[b].z + u.z, acc[b].w + u.w};
            *reinterpret_cast<float4*>(ysp + (((size_t)hc * B + b) * E + e) * D + dgrp * 4) = r;
        }
    }
}

// ---------------- K5: reduce ys partials + b2 (float4) ----------------
// grid: B*E*D/4/256 = 48 blocks
__global__ __launch_bounds__(256) void k_ysred(const float* __restrict__ ysp,
                                               const float* __restrict__ b2,
                                               float* __restrict__ ys) {
    const int i4 = blockIdx.x * 256 + threadIdx.x;   // over B*E*D/4
    const int rem4 = i4 % (E * D / 4);
    float4 v = *reinterpret_cast<const float4*>(b2 + (size_t)rem4 * 4);
#pragma unroll 8
    for (int p = 0; p < NHC; ++p) {
        const float4 u = *reinterpret_cast<const float4*>(ysp + (size_t)p * B * E * D + (size_t)i4 * 4);
        v.x += u.x; v.y += u.y; v.z += u.z; v.w += u.w;
    }
    *reinterpret_cast<float4*>(ys + (size_t)i4 * 4) = v;
}

// ---------------- K6: combine ----------------
// grid: B*S/8 = 2048 blocks, 192 threads; block handles 8 s-rows; ys hoisted to regs
__global__ __launch_bounds__(192) void k_combine(const float* __restrict__ logits,
                                                 const float* __restrict__ cmax,
                                                 const float* __restrict__ csum,
                                                 const float* __restrict__ ys,
                                                 float* __restrict__ y) {
    const int blk = blockIdx.x;
    const int b = blk / (S / 8);
    const int s0 = (blk % (S / 8)) * 8;
    const int t = threadIdx.x;
    const int d4 = t * 4;

    float4 ysr[16];
    float cm[16], ci[16];
#pragma unroll
    for (int n = 0; n < 16; ++n) {
        ysr[n] = *reinterpret_cast<const float4*>(ys + ((size_t)b * N + n) * D + d4);
        cm[n] = cmax[b * N + n];
        ci[n] = 1.0f / csum[b * N + n];
    }
#pragma unroll
    for (int r = 0; r < 8; ++r) {
        const int s = s0 + r;
        const float* lrow = logits + ((size_t)b * S + s) * N;
        float4 acc{0, 0, 0, 0};
#pragma unroll
        for (int n = 0; n < 16; ++n) {
            const float cw = __expf(lrow[n] - cm[n]) * ci[n];
            acc.x = fmaf(cw, ysr[n].x, acc.x);
            acc.y = fmaf(cw, ysr[n].y, acc.y);
            acc.z = fmaf(cw, ysr[n].z, acc.z);
            acc.w = fmaf(cw, ysr[n].w, acc.w);
        }
        *reinterpret_cast<float4*>(y + ((size_t)b * S + s) * D + d4) = acc;
    }
}

extern "C" void kernel_launch(void* const* d_in, const int* in_sizes, int n_in,
                              void* d_out, int out_size, void* d_ws, size_t ws_size,
                              hipStream_t stream) {
    const float* x   = (const float*)d_in[0];
    const float* phi = (const float*)d_in[1];
    const float* W1  = (const float*)d_in[2];
    const float* b1  = (const float*)d_in[3];
    const float* W2  = (const float*)d_in[4];
    const float* b2  = (const float*)d_in[5];
    float* y = (float*)d_out;
    float* ws = (float*)d_ws;

    float* logits = ws + OFF_LOG;
    float* dw     = ws + OFF_DW;
    float* pcm    = ws + OFF_PCM;
    float* pcs    = ws + OFF_PCS;
    float* cmax   = ws + OFF_CMAX;
    float* csum   = ws + OFF_CSUM;
    float* xsp    = ws + OFF_XSP;
    float* xs     = ws + OFF_XS;
    float* ysp    = ws + OFF_YSP;
    float* ys     = ws + OFF_YS;

    k_logits<<<B * LPB, 256, 0, stream>>>(x, phi, logits, dw, pcm, pcs);
    k_xsp<<<B * NSCH, 192, 0, stream>>>(x, dw, xsp);
    k_xsred_cmerge<<<193, 256, 0, stream>>>(xsp, xs, pcm, pcs, cmax, csum);
    k_ffn<<<E * NHC, 384, 0, stream>>>(xs, W1, b1, W2, ysp);
    k_ysred<<<48, 256, 0, stream>>>(ysp, b2, ys);
    k_combine<<<B * (S / 8), 192, 0, stream>>>(logits, cmax, csum, ys, y);
}